// Round 7
// baseline (328.523 us; speedup 1.0000x reference)
//
#include <hip/hip_runtime.h>
#include <math.h>

// ---- problem constants (match reference) ----
#define N_NODES 50000
#define N_EDGES 800000
#define IN_DIM  128
#define HEADS   4
#define OUT_DIM 16
#define HD      64          // HEADS*OUT_DIM
#define NEG_SLOPE 0.2f
#define CAP     128         // per-node LDS score cache (deg > CAP -> slow path)
#define LOG2E   1.44269504088896340736f

// hardware 2^x (v_exp_f32); avoids glibc __exp2f name collision
__device__ __forceinline__ float hw_exp2(float x) {
    return __builtin_amdgcn_exp2f(x);
}

// ---------------------------------------------------------------------------
// K1: node projections  xl = x@Wl+bl, xr = x@Wr+br, xres = x@Wres+bres
// grid = 3125 x 256: 16 nodes/block, 4 nodes per wave, col = lane.
// Also zeroes count[] (first 50000 threads) so k0 launch is not needed.
// k-loop unrolled x8 for deep load pipelining (no atomics -> no barrier drain).
// ---------------------------------------------------------------------------
__global__ __launch_bounds__(256)
void k1_proj(const float* __restrict__ x,
             const float* __restrict__ Wl, const float* __restrict__ bl,
             const float* __restrict__ Wr, const float* __restrict__ br,
             const float* __restrict__ Wres, const float* __restrict__ bres,
             int* __restrict__ count,
             float* __restrict__ xl, float* __restrict__ xr,
             float* __restrict__ xres) {
    __shared__ float xs[16][IN_DIM];
    const int base = blockIdx.x * 16;

    // free count-zeroing (replaces k0): 3125*256 = 800000 >= N_NODES
    const int gid = blockIdx.x * 256 + threadIdx.x;
    if (gid < N_NODES) count[gid] = 0;

    {
        const float4* s4 = (const float4*)(x + (size_t)base * IN_DIM);
        float4* d4 = (float4*)&xs[0][0];
        for (int i = threadIdx.x; i < 16 * IN_DIM / 4; i += 256) d4[i] = s4[i];
    }
    __syncthreads();

    const int group = threadIdx.x >> 6;   // wave id: nodes base+group*4 ..+3
    const int col   = threadIdx.x & 63;

    float al[4] = {0, 0, 0, 0}, ar[4] = {0, 0, 0, 0}, as[4] = {0, 0, 0, 0};
#pragma unroll 8
    for (int k0 = 0; k0 < IN_DIM; k0 += 4) {
        float xv[4][4];
        *(float4*)xv[0] = *(const float4*)&xs[group * 4 + 0][k0];
        *(float4*)xv[1] = *(const float4*)&xs[group * 4 + 1][k0];
        *(float4*)xv[2] = *(const float4*)&xs[group * 4 + 2][k0];
        *(float4*)xv[3] = *(const float4*)&xs[group * 4 + 3][k0];
#pragma unroll
        for (int kk = 0; kk < 4; ++kk) {
            const float wl = Wl[(k0 + kk) * HD + col];
            const float wr = Wr[(k0 + kk) * HD + col];
            const float ws = Wres[(k0 + kk) * HD + col];
#pragma unroll
            for (int i = 0; i < 4; ++i) {
                al[i] += xv[i][kk] * wl;
                ar[i] += xv[i][kk] * wr;
                as[i] += xv[i][kk] * ws;
            }
        }
    }
    const float blv = bl[col], brv = br[col], bsv = bres[col];
    const size_t n0 = (size_t)(base + group * 4) * HD + col;
#pragma unroll
    for (int i = 0; i < 4; ++i) {
        xl[n0 + i * HD]   = al[i] + blv;
        xr[n0 + i * HD]   = ar[i] + brv;
        xres[n0 + i * HD] = as[i] + bsv;
    }
}

// ---------------------------------------------------------------------------
// K2: histogram of dst (separate kernel: atomics stay off k1's barrier path)
// ---------------------------------------------------------------------------
__global__ __launch_bounds__(256)
void k2_hist(const int* __restrict__ dst, int* __restrict__ count) {
    int e = blockIdx.x * blockDim.x + threadIdx.x;
    if (e < N_EDGES) atomicAdd(&count[dst[e]], 1);
}

// ---------------------------------------------------------------------------
// K3a/b/c: two-level exclusive scan of count -> rowptr (and cursor copy)
// ---------------------------------------------------------------------------
#define SCAN_BLOCKS 196   // ceil(50000/256)

__global__ __launch_bounds__(256)
void k3a_scan1(const int* __restrict__ count, int* __restrict__ incl,
               int* __restrict__ bsum) {
    __shared__ int s[256];
    const int t = threadIdx.x;
    const int i = blockIdx.x * 256 + t;
    int c = (i < N_NODES) ? count[i] : 0;
    s[t] = c;
    __syncthreads();
    for (int off = 1; off < 256; off <<= 1) {
        int v = (t >= off) ? s[t - off] : 0;
        __syncthreads();
        s[t] += v;
        __syncthreads();
    }
    if (i < N_NODES) incl[i] = s[t];
    if (t == 255) bsum[blockIdx.x] = s[255];
}

__global__ __launch_bounds__(256)
void k3b_scan2(int* __restrict__ bsum, int* __restrict__ boff) {
    __shared__ int s[256];
    const int t = threadIdx.x;
    int c = (t < SCAN_BLOCKS) ? bsum[t] : 0;
    s[t] = c;
    __syncthreads();
    for (int off = 1; off < 256; off <<= 1) {
        int v = (t >= off) ? s[t - off] : 0;
        __syncthreads();
        s[t] += v;
        __syncthreads();
    }
    if (t < SCAN_BLOCKS) boff[t] = s[t] - c;   // exclusive
}

__global__ __launch_bounds__(256)
void k3c_scan3(const int* __restrict__ count, int* __restrict__ incl /*->rowptr*/,
               const int* __restrict__ boff, int* __restrict__ cursor) {
    const int i = blockIdx.x * 256 + threadIdx.x;
    if (i >= N_NODES) return;
    const int v = incl[i] - count[i] + boff[blockIdx.x];  // exclusive prefix
    incl[i] = v;       // rowptr
    cursor[i] = v;
}

// ---------------------------------------------------------------------------
// K4: scatter packed edge records (eid, src, ea) into CSR order — ONE 16B
//     scattered write per edge. Also emits edge_index output (float).
// ---------------------------------------------------------------------------
__global__ __launch_bounds__(256)
void k4_scatter(const int* __restrict__ src, const int* __restrict__ dst,
                const float* __restrict__ ea,
                int* __restrict__ cursor, int4* __restrict__ recs,
                float* __restrict__ out_ei) {
    int e = blockIdx.x * blockDim.x + threadIdx.x;
    if (e >= N_EDGES) return;
    const int d = dst[e];
    const int s = src[e];
    const int pos = atomicAdd(&cursor[d], 1);
    recs[pos] = make_int4(e, s, __float_as_int(ea[e]), 0);
    out_ei[e] = (float)s;
    out_ei[N_EDGES + e] = (float)d;
}

// ---------------------------------------------------------------------------
// K5: fused per-node GATv2. One wave per node; 4 edges in flight
//     (4 groups x 16 lanes; lane u owns hd = 4u..4u+3 as float4).
//     One-exp online softmax (exp2-folded), groups flash-merge via shfl_xor.
// ---------------------------------------------------------------------------
__global__ __launch_bounds__(256)
void k5_node(const int4* __restrict__ recs,
             const int* __restrict__ rowptr, const int* __restrict__ count,
             const float* __restrict__ xl, const float* __restrict__ xr,
             const float* __restrict__ xres,
             const float* __restrict__ We, const float* __restrict__ att,
             const float* __restrict__ bias_out,
             float* __restrict__ out, float* __restrict__ out_alpha) {
    __shared__ float sc_lds[4][CAP][HEADS];   // 8 KB  (scores pre-scaled by log2e)

    const int wv   = threadIdx.x >> 6;
    const int lane = threadIdx.x & 63;
    const int u    = lane & 15;           // position in group (hd = 4u..4u+3)
    const int g    = lane >> 4;           // edge group 0..3
    const int n    = blockIdx.x * 4 + wv; // grid exact: 12500*4 = 50000

    const int base = rowptr[n];
    const int deg  = count[n];

    const float4 xr4 = *(const float4*)(xr  + (size_t)n * HD + 4 * u);
    const float4 We4 = *(const float4*)(We  + 4 * u);
    float4 at4       = *(const float4*)(att + 4 * u);
    at4.x *= LOG2E; at4.y *= LOG2E; at4.z *= LOG2E; at4.w *= LOG2E;

    float m = -INFINITY, dsum = 0.f;
    float4 acc = make_float4(0.f, 0.f, 0.f, 0.f);

    for (int c0 = 0; c0 < deg; c0 += 64) {
        const int nrem = min(64, deg - c0);
        int s_my = 0; float a_my = 0.f;
        if (lane < nrem) {
            const int4 r = recs[base + c0 + lane];   // coalesced 16B
            s_my = r.y;
            a_my = __int_as_float(r.z);
        }
        const int nchunk = (nrem + 3) >> 2;

        // prefetch chunk 0 for this group
        int   j   = g;
        bool  v   = j < nrem;
        int   s   = __shfl(s_my, j);
        float aev = __shfl(a_my, j);
        float4 xlv = make_float4(0.f, 0.f, 0.f, 0.f);
        if (v) xlv = *(const float4*)(xl + (size_t)s * HD + 4 * u);

        for (int c = 0; c < nchunk; ++c) {
            const float4 cur  = xlv;
            const bool   curv = v;
            const float  ca   = aev;
            const int    cj   = 4 * c + g;
            // prefetch next chunk
            j = 4 * (c + 1) + g;
            v = j < nrem;
            s   = __shfl(s_my, j & 63);
            aev = __shfl(a_my, j & 63);
            if (v) xlv = *(const float4*)(xl + (size_t)s * HD + 4 * u);

            if (curv) {
                float f0 = cur.x + xr4.x + ca * We4.x;
                float f1 = cur.y + xr4.y + ca * We4.y;
                float f2 = cur.z + xr4.z + ca * We4.z;
                float f3 = cur.w + xr4.w + ca * We4.w;
                f0 = f0 > 0.f ? f0 : NEG_SLOPE * f0;
                f1 = f1 > 0.f ? f1 : NEG_SLOPE * f1;
                f2 = f2 > 0.f ? f2 : NEG_SLOPE * f2;
                f3 = f3 > 0.f ? f3 : NEG_SLOPE * f3;
                float p = f0 * at4.x + f1 * at4.y + f2 * at4.z + f3 * at4.w;
                p += __shfl_xor(p, 1);
                p += __shfl_xor(p, 2);     // per-head log2-scaled score
                const int jj = c0 + cj;
                if (jj < CAP && (u & 3) == 0) sc_lds[wv][jj][u >> 2] = p;
                // one-exp online update: t = 2^(-|p-m|)
                const float t    = hw_exp2(-fabsf(p - m));   // m=-inf -> 0
                const bool  up   = (p >= m);
                const float scl  = up ? t : 1.f;
                const float pe   = up ? 1.f : t;
                m = fmaxf(m, p);
                dsum  = dsum * scl + pe;
                acc.x = acc.x * scl + pe * cur.x;
                acc.y = acc.y * scl + pe * cur.y;
                acc.z = acc.z * scl + pe * cur.z;
                acc.w = acc.w * scl + pe * cur.w;
            }
        }
    }

    // flash-merge the 4 groups (lanes u, u+16, u+32, u+48 share an hd slice)
#pragma unroll
    for (int off = 16; off <= 32; off <<= 1) {
        const float mo = __shfl_xor(m, off);
        const float d2 = __shfl_xor(dsum, off);
        float4 a2;
        a2.x = __shfl_xor(acc.x, off);
        a2.y = __shfl_xor(acc.y, off);
        a2.z = __shfl_xor(acc.z, off);
        a2.w = __shfl_xor(acc.w, off);
        const float mm = fmaxf(m, mo);
        const float s1 = (m  == -INFINITY) ? 0.f : hw_exp2(m - mm);
        const float s2 = (mo == -INFINITY) ? 0.f : hw_exp2(mo - mm);
        dsum  = dsum * s1 + d2 * s2;
        acc.x = acc.x * s1 + a2.x * s2;
        acc.y = acc.y * s1 + a2.y * s2;
        acc.z = acc.z * s1 + a2.z * s2;
        acc.w = acc.w * s1 + a2.w * s2;
        m = mm;
    }
    const float inv = 1.f / (dsum + 1e-16f);

    // broadcast per-head m / inv (head h lives at lane 4h)
    const float m0 = __shfl(m, 0),  m1 = __shfl(m, 4);
    const float m2 = __shfl(m, 8),  m3 = __shfl(m, 12);
    const float i0 = __shfl(inv, 0), i1 = __shfl(inv, 4);
    const float i2 = __shfl(inv, 8), i3 = __shfl(inv, 12);

    __syncthreads();   // sc_lds visibility (uniform; each wave touches own slice)

    // alpha write pass (original edge order via record.eid)
    for (int jj = lane; jj < deg; jj += 64) {
        const int4 r = recs[base + jj];
        const int  e = r.x;
        float s0, s1, s2, s3;
        if (jj < CAP) {
            const float4 sc4 = *(const float4*)&sc_lds[wv][jj][0];
            s0 = sc4.x; s1 = sc4.y; s2 = sc4.z; s3 = sc4.w;
        } else {
            // slow path (deg > CAP): recompute from globals (log2-scaled)
            const int   sN  = r.y;
            const float aev = __int_as_float(r.z);
            float sc[4];
            for (int h2 = 0; h2 < 4; ++h2) {
                float a2 = 0.f;
                for (int d2 = 0; d2 < 16; ++d2) {
                    const int hd2 = h2 * 16 + d2;
                    float f = xl[(size_t)sN * HD + hd2] + xr[(size_t)n * HD + hd2]
                              + aev * We[hd2];
                    f = f > 0.f ? f : NEG_SLOPE * f;
                    a2 += f * att[hd2];
                }
                sc[h2] = a2 * LOG2E;
            }
            s0 = sc[0]; s1 = sc[1]; s2 = sc[2]; s3 = sc[3];
        }
        float4 a4;
        a4.x = hw_exp2(s0 - m0) * i0;
        a4.y = hw_exp2(s1 - m1) * i1;
        a4.z = hw_exp2(s2 - m2) * i2;
        a4.w = hw_exp2(s3 - m3) * i3;
        *(float4*)(out_alpha + (size_t)e * HEADS) = a4;
    }

    // final output (merged acc identical in all groups; group 0 writes)
    if (g == 0) {
        const float4 xs4 = *(const float4*)(xres + (size_t)n * HD + 4 * u);
        const float4 b4  = *(const float4*)(bias_out + 4 * u);
        float4 o;
        o.x = acc.x * inv + b4.x + xs4.x;
        o.y = acc.y * inv + b4.y + xs4.y;
        o.z = acc.z * inv + b4.z + xs4.z;
        o.w = acc.w * inv + b4.w + xs4.w;
        o.x = o.x > 0.f ? o.x : __expf(o.x) - 1.f;
        o.y = o.y > 0.f ? o.y : __expf(o.y) - 1.f;
        o.z = o.z > 0.f ? o.z : __expf(o.z) - 1.f;
        o.w = o.w > 0.f ? o.w : __expf(o.w) - 1.f;
        *(float4*)(out + (size_t)n * HD + 4 * u) = o;
    }
}

// ---------------------------------------------------------------------------
extern "C" void kernel_launch(void* const* d_in, const int* in_sizes, int n_in,
                              void* d_out, int out_size, void* d_ws, size_t ws_size,
                              hipStream_t stream) {
    const float* x        = (const float*)d_in[0];
    const int*   ei       = (const int*)d_in[1];
    const float* ea       = (const float*)d_in[2];
    const float* Wl       = (const float*)d_in[3];
    const float* bl       = (const float*)d_in[4];
    const float* Wr       = (const float*)d_in[5];
    const float* br       = (const float*)d_in[6];
    const float* We       = (const float*)d_in[7];
    const float* att      = (const float*)d_in[8];
    const float* bias_out = (const float*)d_in[9];
    const float* Wres     = (const float*)d_in[10];
    const float* bres     = (const float*)d_in[11];

    const int* src = ei;
    const int* dst = ei + N_EDGES;

    // output layout (tuple concat, float32): out | edge_index | alpha
    float* out       = (float*)d_out;
    float* out_ei    = out + (size_t)N_NODES * HD;
    float* out_alpha = out_ei + 2 * (size_t)N_EDGES;

    // workspace layout
    float* ws   = (float*)d_ws;
    float* xl   = ws;                               // N*HD
    float* xr   = xl + (size_t)N_NODES * HD;        // N*HD
    float* xres = xr + (size_t)N_NODES * HD;        // N*HD
    int* ibuf   = (int*)(xres + (size_t)N_NODES * HD);
    int* count  = ibuf;                             // N
    int* rowptr = count + N_NODES;                  // N
    int* cursor = rowptr + N_NODES;                 // N
    int* bsum   = cursor + N_NODES;                 // SCAN_BLOCKS
    int* boff   = bsum + SCAN_BLOCKS;               // SCAN_BLOCKS
    // 16B-align the record array
    size_t recoff = (size_t)(boff + SCAN_BLOCKS - (int*)d_ws);
    recoff = (recoff + 3) & ~(size_t)3;
    int4* recs  = (int4*)((int*)d_ws + recoff);     // E records (16B each)

    k1_proj<<<N_NODES / 16, 256, 0, stream>>>(x, Wl, bl, Wr, br, Wres, bres,
                                              count, xl, xr, xres);
    k2_hist<<<N_EDGES / 256, 256, 0, stream>>>(dst, count);
    k3a_scan1<<<SCAN_BLOCKS, 256, 0, stream>>>(count, rowptr, bsum);
    k3b_scan2<<<1, 256, 0, stream>>>(bsum, boff);
    k3c_scan3<<<SCAN_BLOCKS, 256, 0, stream>>>(count, rowptr, boff, cursor);
    k4_scatter<<<(N_EDGES + 255) / 256, 256, 0, stream>>>(src, dst, ea, cursor,
                                                          recs, out_ei);
    k5_node<<<N_NODES / 4, 256, 0, stream>>>(recs, rowptr, count,
                                             xl, xr, xres, We, att, bias_out,
                                             out, out_alpha);
}

// Round 8
// 317.610 us; speedup vs baseline: 1.0344x; 1.0344x over previous
//
#include <hip/hip_runtime.h>
#include <math.h>

// ---- problem constants (match reference) ----
#define N_NODES 50000
#define N_EDGES 800000
#define IN_DIM  128
#define HEADS   4
#define OUT_DIM 16
#define HD      64          // HEADS*OUT_DIM
#define NEG_SLOPE 0.2f
#define CAP     128         // per-node LDS score cache (deg > CAP -> slow path)
#define LOG2E   1.44269504088896340736f

// hardware 2^x (v_exp_f32); avoids glibc __exp2f name collision
__device__ __forceinline__ float hw_exp2(float x) {
    return __builtin_amdgcn_exp2f(x);
}

// ---------------------------------------------------------------------------
// K1: node projections as a register-tiled GEMM fragment.
// 32 nodes/block (4 waves x 8 nodes). Lane = (g,u): u=col-quad (cols 4u..4u+3),
// g=k-phase (k == g mod 4). Per 4-k iter: 3 float4 W loads + 2 ds_read_b128,
// 96 FMAs. Partial sums merged across g via shfl_xor. Also zeroes count[].
// ---------------------------------------------------------------------------
__global__ __launch_bounds__(256)
void k1_proj(const float* __restrict__ x,
             const float* __restrict__ Wl, const float* __restrict__ bl,
             const float* __restrict__ Wr, const float* __restrict__ br,
             const float* __restrict__ Wres, const float* __restrict__ bres,
             int* __restrict__ count,
             float* __restrict__ xl, float* __restrict__ xr,
             float* __restrict__ xres) {
    __shared__ float xsT[IN_DIM][36];   // transposed x tile, pad->conflict-free reads
    const int base = blockIdx.x * 32;

    // free count-zeroing (replaces k0): 1563*256 = 400128 >= N_NODES
    const int gid = blockIdx.x * 256 + threadIdx.x;
    if (gid < N_NODES) count[gid] = 0;

    // stage x transposed: thread reads 4 consecutive float4 (64B) of one row
    {
        const float4* x4 = (const float4*)x;
#pragma unroll
        for (int r = 0; r < 4; ++r) {
            const int E    = threadIdx.x * 4 + r;   // float4 index in tile
            const int node = E >> 5;                // 32 float4 per node row
            const int kq   = E & 31;
            float4 v = make_float4(0.f, 0.f, 0.f, 0.f);
            if (base + node < N_NODES) v = x4[(size_t)(base + node) * 32 + kq];
            xsT[4 * kq + 0][node] = v.x;
            xsT[4 * kq + 1][node] = v.y;
            xsT[4 * kq + 2][node] = v.z;
            xsT[4 * kq + 3][node] = v.w;
        }
    }
    __syncthreads();

    const int lane = threadIdx.x & 63;
    const int wv   = threadIdx.x >> 6;
    const int u    = lane & 15;          // col-quad: cols 4u..4u+3
    const int g    = lane >> 4;          // k-phase 0..3
    const int n0   = wv * 8;             // first of this wave's 8 nodes

    float4 aL[8], aR[8], aS[8];
#pragma unroll
    for (int i = 0; i < 8; ++i) {
        aL[i] = make_float4(0.f, 0.f, 0.f, 0.f);
        aR[i] = make_float4(0.f, 0.f, 0.f, 0.f);
        aS[i] = make_float4(0.f, 0.f, 0.f, 0.f);
    }

    const float* pL = Wl   + g * HD + 4 * u;
    const float* pR = Wr   + g * HD + 4 * u;
    const float* pS = Wres + g * HD + 4 * u;

#pragma unroll 2
    for (int k0 = 0; k0 < IN_DIM; k0 += 4) {
        const int k = k0 + g;
        const float4 wl4 = *(const float4*)(pL + k0 * HD);
        const float4 wr4 = *(const float4*)(pR + k0 * HD);
        const float4 ws4 = *(const float4*)(pS + k0 * HD);
        const float4 xa  = *(const float4*)&xsT[k][n0];       // nodes n0..n0+3
        const float4 xb  = *(const float4*)&xsT[k][n0 + 4];   // nodes n0+4..n0+7
        const float xn[8] = {xa.x, xa.y, xa.z, xa.w, xb.x, xb.y, xb.z, xb.w};
#pragma unroll
        for (int i = 0; i < 8; ++i) {
            aL[i].x += xn[i] * wl4.x; aL[i].y += xn[i] * wl4.y;
            aL[i].z += xn[i] * wl4.z; aL[i].w += xn[i] * wl4.w;
            aR[i].x += xn[i] * wr4.x; aR[i].y += xn[i] * wr4.y;
            aR[i].z += xn[i] * wr4.z; aR[i].w += xn[i] * wr4.w;
            aS[i].x += xn[i] * ws4.x; aS[i].y += xn[i] * ws4.y;
            aS[i].z += xn[i] * ws4.z; aS[i].w += xn[i] * ws4.w;
        }
    }

    // merge partial sums across the 4 k-phases (lane bits 4-5)
#pragma unroll
    for (int off = 16; off <= 32; off <<= 1) {
#pragma unroll
        for (int i = 0; i < 8; ++i) {
            aL[i].x += __shfl_xor(aL[i].x, off); aL[i].y += __shfl_xor(aL[i].y, off);
            aL[i].z += __shfl_xor(aL[i].z, off); aL[i].w += __shfl_xor(aL[i].w, off);
            aR[i].x += __shfl_xor(aR[i].x, off); aR[i].y += __shfl_xor(aR[i].y, off);
            aR[i].z += __shfl_xor(aR[i].z, off); aR[i].w += __shfl_xor(aR[i].w, off);
            aS[i].x += __shfl_xor(aS[i].x, off); aS[i].y += __shfl_xor(aS[i].y, off);
            aS[i].z += __shfl_xor(aS[i].z, off); aS[i].w += __shfl_xor(aS[i].w, off);
        }
    }

    if (g == 0) {
        const float4 bl4 = *(const float4*)(bl   + 4 * u);
        const float4 br4 = *(const float4*)(br   + 4 * u);
        const float4 bs4 = *(const float4*)(bres + 4 * u);
#pragma unroll
        for (int i = 0; i < 8; ++i) {
            const int node = base + n0 + i;
            if (node < N_NODES) {
                float4 o;
                const size_t off0 = (size_t)node * HD + 4 * u;
                o.x = aL[i].x + bl4.x; o.y = aL[i].y + bl4.y;
                o.z = aL[i].z + bl4.z; o.w = aL[i].w + bl4.w;
                *(float4*)(xl + off0) = o;
                o.x = aR[i].x + br4.x; o.y = aR[i].y + br4.y;
                o.z = aR[i].z + br4.z; o.w = aR[i].w + br4.w;
                *(float4*)(xr + off0) = o;
                o.x = aS[i].x + bs4.x; o.y = aS[i].y + bs4.y;
                o.z = aS[i].z + bs4.z; o.w = aS[i].w + bs4.w;
                *(float4*)(xres + off0) = o;
            }
        }
    }
}

// ---------------------------------------------------------------------------
// K2: histogram of dst (separate kernel: atomics stay off k1's barrier path)
// ---------------------------------------------------------------------------
__global__ __launch_bounds__(256)
void k2_hist(const int* __restrict__ dst, int* __restrict__ count) {
    int e = blockIdx.x * blockDim.x + threadIdx.x;
    if (e < N_EDGES) atomicAdd(&count[dst[e]], 1);
}

// ---------------------------------------------------------------------------
// K3a/b/c: two-level exclusive scan of count -> rowptr (and cursor copy)
// ---------------------------------------------------------------------------
#define SCAN_BLOCKS 196   // ceil(50000/256)

__global__ __launch_bounds__(256)
void k3a_scan1(const int* __restrict__ count, int* __restrict__ incl,
               int* __restrict__ bsum) {
    __shared__ int s[256];
    const int t = threadIdx.x;
    const int i = blockIdx.x * 256 + t;
    int c = (i < N_NODES) ? count[i] : 0;
    s[t] = c;
    __syncthreads();
    for (int off = 1; off < 256; off <<= 1) {
        int v = (t >= off) ? s[t - off] : 0;
        __syncthreads();
        s[t] += v;
        __syncthreads();
    }
    if (i < N_NODES) incl[i] = s[t];
    if (t == 255) bsum[blockIdx.x] = s[255];
}

__global__ __launch_bounds__(256)
void k3b_scan2(int* __restrict__ bsum, int* __restrict__ boff) {
    __shared__ int s[256];
    const int t = threadIdx.x;
    int c = (t < SCAN_BLOCKS) ? bsum[t] : 0;
    s[t] = c;
    __syncthreads();
    for (int off = 1; off < 256; off <<= 1) {
        int v = (t >= off) ? s[t - off] : 0;
        __syncthreads();
        s[t] += v;
        __syncthreads();
    }
    if (t < SCAN_BLOCKS) boff[t] = s[t] - c;   // exclusive
}

__global__ __launch_bounds__(256)
void k3c_scan3(const int* __restrict__ count, int* __restrict__ incl /*->rowptr*/,
               const int* __restrict__ boff, int* __restrict__ cursor) {
    const int i = blockIdx.x * 256 + threadIdx.x;
    if (i >= N_NODES) return;
    const int v = incl[i] - count[i] + boff[blockIdx.x];  // exclusive prefix
    incl[i] = v;       // rowptr
    cursor[i] = v;
}

// ---------------------------------------------------------------------------
// K4: scatter packed edge records (eid, src, ea) into CSR order — ONE 16B
//     scattered write per edge. Also emits edge_index output (float).
// ---------------------------------------------------------------------------
__global__ __launch_bounds__(256)
void k4_scatter(const int* __restrict__ src, const int* __restrict__ dst,
                const float* __restrict__ ea,
                int* __restrict__ cursor, int4* __restrict__ recs,
                float* __restrict__ out_ei) {
    int e = blockIdx.x * blockDim.x + threadIdx.x;
    if (e >= N_EDGES) return;
    const int d = dst[e];
    const int s = src[e];
    const int pos = atomicAdd(&cursor[d], 1);
    recs[pos] = make_int4(e, s, __float_as_int(ea[e]), 0);
    out_ei[e] = (float)s;
    out_ei[N_EDGES + e] = (float)d;
}

// ---------------------------------------------------------------------------
// K5: fused per-node GATv2. One wave per node; 4 edges in flight
//     (4 groups x 16 lanes; lane u owns hd = 4u..4u+3 as float4).
//     One-exp online softmax (exp2-folded), groups flash-merge via shfl_xor.
// ---------------------------------------------------------------------------
__global__ __launch_bounds__(256)
void k5_node(const int4* __restrict__ recs,
             const int* __restrict__ rowptr, const int* __restrict__ count,
             const float* __restrict__ xl, const float* __restrict__ xr,
             const float* __restrict__ xres,
             const float* __restrict__ We, const float* __restrict__ att,
             const float* __restrict__ bias_out,
             float* __restrict__ out, float* __restrict__ out_alpha) {
    __shared__ float sc_lds[4][CAP][HEADS];   // 8 KB  (scores pre-scaled by log2e)

    const int wv   = threadIdx.x >> 6;
    const int lane = threadIdx.x & 63;
    const int u    = lane & 15;           // position in group (hd = 4u..4u+3)
    const int g    = lane >> 4;           // edge group 0..3
    const int n    = blockIdx.x * 4 + wv; // grid exact: 12500*4 = 50000

    const int base = rowptr[n];
    const int deg  = count[n];

    const float4 xr4 = *(const float4*)(xr  + (size_t)n * HD + 4 * u);
    const float4 We4 = *(const float4*)(We  + 4 * u);
    float4 at4       = *(const float4*)(att + 4 * u);
    at4.x *= LOG2E; at4.y *= LOG2E; at4.z *= LOG2E; at4.w *= LOG2E;

    float m = -INFINITY, dsum = 0.f;
    float4 acc = make_float4(0.f, 0.f, 0.f, 0.f);

    for (int c0 = 0; c0 < deg; c0 += 64) {
        const int nrem = min(64, deg - c0);
        int s_my = 0; float a_my = 0.f;
        if (lane < nrem) {
            const int4 r = recs[base + c0 + lane];   // coalesced 16B
            s_my = r.y;
            a_my = __int_as_float(r.z);
        }
        const int nchunk = (nrem + 3) >> 2;

        // prefetch chunk 0 for this group
        int   j   = g;
        bool  v   = j < nrem;
        int   s   = __shfl(s_my, j);
        float aev = __shfl(a_my, j);
        float4 xlv = make_float4(0.f, 0.f, 0.f, 0.f);
        if (v) xlv = *(const float4*)(xl + (size_t)s * HD + 4 * u);

        for (int c = 0; c < nchunk; ++c) {
            const float4 cur  = xlv;
            const bool   curv = v;
            const float  ca   = aev;
            const int    cj   = 4 * c + g;
            // prefetch next chunk
            j = 4 * (c + 1) + g;
            v = j < nrem;
            s   = __shfl(s_my, j & 63);
            aev = __shfl(a_my, j & 63);
            if (v) xlv = *(const float4*)(xl + (size_t)s * HD + 4 * u);

            if (curv) {
                float f0 = cur.x + xr4.x + ca * We4.x;
                float f1 = cur.y + xr4.y + ca * We4.y;
                float f2 = cur.z + xr4.z + ca * We4.z;
                float f3 = cur.w + xr4.w + ca * We4.w;
                f0 = f0 > 0.f ? f0 : NEG_SLOPE * f0;
                f1 = f1 > 0.f ? f1 : NEG_SLOPE * f1;
                f2 = f2 > 0.f ? f2 : NEG_SLOPE * f2;
                f3 = f3 > 0.f ? f3 : NEG_SLOPE * f3;
                float p = f0 * at4.x + f1 * at4.y + f2 * at4.z + f3 * at4.w;
                p += __shfl_xor(p, 1);
                p += __shfl_xor(p, 2);     // per-head log2-scaled score
                const int jj = c0 + cj;
                if (jj < CAP && (u & 3) == 0) sc_lds[wv][jj][u >> 2] = p;
                // one-exp online update: t = 2^(-|p-m|)
                const float t    = hw_exp2(-fabsf(p - m));   // m=-inf -> 0
                const bool  up   = (p >= m);
                const float scl  = up ? t : 1.f;
                const float pe   = up ? 1.f : t;
                m = fmaxf(m, p);
                dsum  = dsum * scl + pe;
                acc.x = acc.x * scl + pe * cur.x;
                acc.y = acc.y * scl + pe * cur.y;
                acc.z = acc.z * scl + pe * cur.z;
                acc.w = acc.w * scl + pe * cur.w;
            }
        }
    }

    // flash-merge the 4 groups (lanes u, u+16, u+32, u+48 share an hd slice)
#pragma unroll
    for (int off = 16; off <= 32; off <<= 1) {
        const float mo = __shfl_xor(m, off);
        const float d2 = __shfl_xor(dsum, off);
        float4 a2;
        a2.x = __shfl_xor(acc.x, off);
        a2.y = __shfl_xor(acc.y, off);
        a2.z = __shfl_xor(acc.z, off);
        a2.w = __shfl_xor(acc.w, off);
        const float mm = fmaxf(m, mo);
        const float s1 = (m  == -INFINITY) ? 0.f : hw_exp2(m - mm);
        const float s2 = (mo == -INFINITY) ? 0.f : hw_exp2(mo - mm);
        dsum  = dsum * s1 + d2 * s2;
        acc.x = acc.x * s1 + a2.x * s2;
        acc.y = acc.y * s1 + a2.y * s2;
        acc.z = acc.z * s1 + a2.z * s2;
        acc.w = acc.w * s1 + a2.w * s2;
        m = mm;
    }
    const float inv = 1.f / (dsum + 1e-16f);

    // broadcast per-head m / inv (head h lives at lane 4h)
    const float m0 = __shfl(m, 0),  m1 = __shfl(m, 4);
    const float m2 = __shfl(m, 8),  m3 = __shfl(m, 12);
    const float i0 = __shfl(inv, 0), i1 = __shfl(inv, 4);
    const float i2 = __shfl(inv, 8), i3 = __shfl(inv, 12);

    __syncthreads();   // sc_lds visibility (uniform; each wave touches own slice)

    // alpha write pass (original edge order via record.eid)
    for (int jj = lane; jj < deg; jj += 64) {
        const int4 r = recs[base + jj];
        const int  e = r.x;
        float s0, s1, s2, s3;
        if (jj < CAP) {
            const float4 sc4 = *(const float4*)&sc_lds[wv][jj][0];
            s0 = sc4.x; s1 = sc4.y; s2 = sc4.z; s3 = sc4.w;
        } else {
            // slow path (deg > CAP): recompute from globals (log2-scaled)
            const int   sN  = r.y;
            const float aev = __int_as_float(r.z);
            float sc[4];
            for (int h2 = 0; h2 < 4; ++h2) {
                float a2 = 0.f;
                for (int d2 = 0; d2 < 16; ++d2) {
                    const int hd2 = h2 * 16 + d2;
                    float f = xl[(size_t)sN * HD + hd2] + xr[(size_t)n * HD + hd2]
                              + aev * We[hd2];
                    f = f > 0.f ? f : NEG_SLOPE * f;
                    a2 += f * att[hd2];
                }
                sc[h2] = a2 * LOG2E;
            }
            s0 = sc[0]; s1 = sc[1]; s2 = sc[2]; s3 = sc[3];
        }
        float4 a4;
        a4.x = hw_exp2(s0 - m0) * i0;
        a4.y = hw_exp2(s1 - m1) * i1;
        a4.z = hw_exp2(s2 - m2) * i2;
        a4.w = hw_exp2(s3 - m3) * i3;
        *(float4*)(out_alpha + (size_t)e * HEADS) = a4;
    }

    // final output (merged acc identical in all groups; group 0 writes)
    if (g == 0) {
        const float4 xs4 = *(const float4*)(xres + (size_t)n * HD + 4 * u);
        const float4 b4  = *(const float4*)(bias_out + 4 * u);
        float4 o;
        o.x = acc.x * inv + b4.x + xs4.x;
        o.y = acc.y * inv + b4.y + xs4.y;
        o.z = acc.z * inv + b4.z + xs4.z;
        o.w = acc.w * inv + b4.w + xs4.w;
        o.x = o.x > 0.f ? o.x : __expf(o.x) - 1.f;
        o.y = o.y > 0.f ? o.y : __expf(o.y) - 1.f;
        o.z = o.z > 0.f ? o.z : __expf(o.z) - 1.f;
        o.w = o.w > 0.f ? o.w : __expf(o.w) - 1.f;
        *(float4*)(out + (size_t)n * HD + 4 * u) = o;
    }
}

// ---------------------------------------------------------------------------
extern "C" void kernel_launch(void* const* d_in, const int* in_sizes, int n_in,
                              void* d_out, int out_size, void* d_ws, size_t ws_size,
                              hipStream_t stream) {
    const float* x        = (const float*)d_in[0];
    const int*   ei       = (const int*)d_in[1];
    const float* ea       = (const float*)d_in[2];
    const float* Wl       = (const float*)d_in[3];
    const float* bl       = (const float*)d_in[4];
    const float* Wr       = (const float*)d_in[5];
    const float* br       = (const float*)d_in[6];
    const float* We       = (const float*)d_in[7];
    const float* att      = (const float*)d_in[8];
    const float* bias_out = (const float*)d_in[9];
    const float* Wres     = (const float*)d_in[10];
    const float* bres     = (const float*)d_in[11];

    const int* src = ei;
    const int* dst = ei + N_EDGES;

    // output layout (tuple concat, float32): out | edge_index | alpha
    float* out       = (float*)d_out;
    float* out_ei    = out + (size_t)N_NODES * HD;
    float* out_alpha = out_ei + 2 * (size_t)N_EDGES;

    // workspace layout
    float* ws   = (float*)d_ws;
    float* xl   = ws;                               // N*HD
    float* xr   = xl + (size_t)N_NODES * HD;        // N*HD
    float* xres = xr + (size_t)N_NODES * HD;        // N*HD
    int* ibuf   = (int*)(xres + (size_t)N_NODES * HD);
    int* count  = ibuf;                             // N
    int* rowptr = count + N_NODES;                  // N
    int* cursor = rowptr + N_NODES;                 // N
    int* bsum   = cursor + N_NODES;                 // SCAN_BLOCKS
    int* boff   = bsum + SCAN_BLOCKS;               // SCAN_BLOCKS
    // 16B-align the record array
    size_t recoff = (size_t)(boff + SCAN_BLOCKS - (int*)d_ws);
    recoff = (recoff + 3) & ~(size_t)3;
    int4* recs  = (int4*)((int*)d_ws + recoff);     // E records (16B each)

    k1_proj<<<(N_NODES + 31) / 32, 256, 0, stream>>>(x, Wl, bl, Wr, br, Wres, bres,
                                                     count, xl, xr, xres);
    k2_hist<<<N_EDGES / 256, 256, 0, stream>>>(dst, count);
    k3a_scan1<<<SCAN_BLOCKS, 256, 0, stream>>>(count, rowptr, bsum);
    k3b_scan2<<<1, 256, 0, stream>>>(bsum, boff);
    k3c_scan3<<<SCAN_BLOCKS, 256, 0, stream>>>(count, rowptr, boff, cursor);
    k4_scatter<<<(N_EDGES + 255) / 256, 256, 0, stream>>>(src, dst, ea, cursor,
                                                          recs, out_ei);
    k5_node<<<N_NODES / 4, 256, 0, stream>>>(recs, rowptr, count,
                                             xl, xr, xres, We, att, bias_out,
                                             out, out_alpha);
}

// Round 9
// 268.648 us; speedup vs baseline: 1.2229x; 1.1823x over previous
//
#include <hip/hip_runtime.h>
#include <math.h>

// ---- problem constants (match reference) ----
#define N_NODES 50000
#define N_EDGES 800000
#define IN_DIM  128
#define HEADS   4
#define OUT_DIM 16
#define HD      64          // HEADS*OUT_DIM
#define NEG_SLOPE 0.2f
#define CAP     128         // per-node LDS score cache (deg > CAP -> slow path)
#define LOG2E   1.44269504088896340736f

// hardware 2^x (v_exp_f32); avoids glibc __exp2f name collision
__device__ __forceinline__ float hw_exp2(float x) {
    return __builtin_amdgcn_exp2f(x);
}

// ---------------------------------------------------------------------------
// K1: node projections as a register-tiled GEMM fragment.
// 32 nodes/block (4 waves x 8 nodes). Lane = (g,u): u=col-quad (cols 4u..4u+3),
// g=k-phase (k == g mod 4). Partial sums merged across g via shfl_xor.
// Also zeroes count[].
// ---------------------------------------------------------------------------
__global__ __launch_bounds__(256)
void k1_proj(const float* __restrict__ x,
             const float* __restrict__ Wl, const float* __restrict__ bl,
             const float* __restrict__ Wr, const float* __restrict__ br,
             const float* __restrict__ Wres, const float* __restrict__ bres,
             int* __restrict__ count,
             float* __restrict__ xl, float* __restrict__ xr,
             float* __restrict__ xres) {
    __shared__ float xsT[IN_DIM][36];   // transposed x tile, pad->conflict-free reads
    const int base = blockIdx.x * 32;

    // free count-zeroing (replaces k0): 1563*256 = 400128 >= N_NODES
    const int gid = blockIdx.x * 256 + threadIdx.x;
    if (gid < N_NODES) count[gid] = 0;

    // stage x transposed: thread reads 4 consecutive float4 (64B) of one row
    {
        const float4* x4 = (const float4*)x;
#pragma unroll
        for (int r = 0; r < 4; ++r) {
            const int E    = threadIdx.x * 4 + r;   // float4 index in tile
            const int node = E >> 5;                // 32 float4 per node row
            const int kq   = E & 31;
            float4 v = make_float4(0.f, 0.f, 0.f, 0.f);
            if (base + node < N_NODES) v = x4[(size_t)(base + node) * 32 + kq];
            xsT[4 * kq + 0][node] = v.x;
            xsT[4 * kq + 1][node] = v.y;
            xsT[4 * kq + 2][node] = v.z;
            xsT[4 * kq + 3][node] = v.w;
        }
    }
    __syncthreads();

    const int lane = threadIdx.x & 63;
    const int wv   = threadIdx.x >> 6;
    const int u    = lane & 15;          // col-quad: cols 4u..4u+3
    const int g    = lane >> 4;          // k-phase 0..3
    const int n0   = wv * 8;             // first of this wave's 8 nodes

    float4 aL[8], aR[8], aS[8];
#pragma unroll
    for (int i = 0; i < 8; ++i) {
        aL[i] = make_float4(0.f, 0.f, 0.f, 0.f);
        aR[i] = make_float4(0.f, 0.f, 0.f, 0.f);
        aS[i] = make_float4(0.f, 0.f, 0.f, 0.f);
    }

    const float* pL = Wl   + g * HD + 4 * u;
    const float* pR = Wr   + g * HD + 4 * u;
    const float* pS = Wres + g * HD + 4 * u;

#pragma unroll 2
    for (int k0 = 0; k0 < IN_DIM; k0 += 4) {
        const int k = k0 + g;
        const float4 wl4 = *(const float4*)(pL + k0 * HD);
        const float4 wr4 = *(const float4*)(pR + k0 * HD);
        const float4 ws4 = *(const float4*)(pS + k0 * HD);
        const float4 xa  = *(const float4*)&xsT[k][n0];       // nodes n0..n0+3
        const float4 xb  = *(const float4*)&xsT[k][n0 + 4];   // nodes n0+4..n0+7
        const float xn[8] = {xa.x, xa.y, xa.z, xa.w, xb.x, xb.y, xb.z, xb.w};
#pragma unroll
        for (int i = 0; i < 8; ++i) {
            aL[i].x += xn[i] * wl4.x; aL[i].y += xn[i] * wl4.y;
            aL[i].z += xn[i] * wl4.z; aL[i].w += xn[i] * wl4.w;
            aR[i].x += xn[i] * wr4.x; aR[i].y += xn[i] * wr4.y;
            aR[i].z += xn[i] * wr4.z; aR[i].w += xn[i] * wr4.w;
            aS[i].x += xn[i] * ws4.x; aS[i].y += xn[i] * ws4.y;
            aS[i].z += xn[i] * ws4.z; aS[i].w += xn[i] * ws4.w;
        }
    }

    // merge partial sums across the 4 k-phases (lane bits 4-5)
#pragma unroll
    for (int off = 16; off <= 32; off <<= 1) {
#pragma unroll
        for (int i = 0; i < 8; ++i) {
            aL[i].x += __shfl_xor(aL[i].x, off); aL[i].y += __shfl_xor(aL[i].y, off);
            aL[i].z += __shfl_xor(aL[i].z, off); aL[i].w += __shfl_xor(aL[i].w, off);
            aR[i].x += __shfl_xor(aR[i].x, off); aR[i].y += __shfl_xor(aR[i].y, off);
            aR[i].z += __shfl_xor(aR[i].z, off); aR[i].w += __shfl_xor(aR[i].w, off);
            aS[i].x += __shfl_xor(aS[i].x, off); aS[i].y += __shfl_xor(aS[i].y, off);
            aS[i].z += __shfl_xor(aS[i].z, off); aS[i].w += __shfl_xor(aS[i].w, off);
        }
    }

    if (g == 0) {
        const float4 bl4 = *(const float4*)(bl   + 4 * u);
        const float4 br4 = *(const float4*)(br   + 4 * u);
        const float4 bs4 = *(const float4*)(bres + 4 * u);
#pragma unroll
        for (int i = 0; i < 8; ++i) {
            const int node = base + n0 + i;
            if (node < N_NODES) {
                float4 o;
                const size_t off0 = (size_t)node * HD + 4 * u;
                o.x = aL[i].x + bl4.x; o.y = aL[i].y + bl4.y;
                o.z = aL[i].z + bl4.z; o.w = aL[i].w + bl4.w;
                *(float4*)(xl + off0) = o;
                o.x = aR[i].x + br4.x; o.y = aR[i].y + br4.y;
                o.z = aR[i].z + br4.z; o.w = aR[i].w + br4.w;
                *(float4*)(xr + off0) = o;
                o.x = aS[i].x + bs4.x; o.y = aS[i].y + bs4.y;
                o.z = aS[i].z + bs4.z; o.w = aS[i].w + bs4.w;
                *(float4*)(xres + off0) = o;
            }
        }
    }
}

// ---------------------------------------------------------------------------
// K2: histogram of dst + per-edge rank (the atomic's return value).
// The rank makes the later scatter atomic-free.
// ---------------------------------------------------------------------------
__global__ __launch_bounds__(256)
void k2_hist(const int* __restrict__ dst, int* __restrict__ count,
             int* __restrict__ rank) {
    int e = blockIdx.x * blockDim.x + threadIdx.x;
    if (e < N_EDGES) rank[e] = atomicAdd(&count[dst[e]], 1);
}

// ---------------------------------------------------------------------------
// K3a/b/c: two-level exclusive scan of count -> rowptr
// ---------------------------------------------------------------------------
#define SCAN_BLOCKS 196   // ceil(50000/256)

__global__ __launch_bounds__(256)
void k3a_scan1(const int* __restrict__ count, int* __restrict__ incl,
               int* __restrict__ bsum) {
    __shared__ int s[256];
    const int t = threadIdx.x;
    const int i = blockIdx.x * 256 + t;
    int c = (i < N_NODES) ? count[i] : 0;
    s[t] = c;
    __syncthreads();
    for (int off = 1; off < 256; off <<= 1) {
        int v = (t >= off) ? s[t - off] : 0;
        __syncthreads();
        s[t] += v;
        __syncthreads();
    }
    if (i < N_NODES) incl[i] = s[t];
    if (t == 255) bsum[blockIdx.x] = s[255];
}

__global__ __launch_bounds__(256)
void k3b_scan2(int* __restrict__ bsum, int* __restrict__ boff) {
    __shared__ int s[256];
    const int t = threadIdx.x;
    int c = (t < SCAN_BLOCKS) ? bsum[t] : 0;
    s[t] = c;
    __syncthreads();
    for (int off = 1; off < 256; off <<= 1) {
        int v = (t >= off) ? s[t - off] : 0;
        __syncthreads();
        s[t] += v;
        __syncthreads();
    }
    if (t < SCAN_BLOCKS) boff[t] = s[t] - c;   // exclusive
}

__global__ __launch_bounds__(256)
void k3c_scan3(const int* __restrict__ count, int* __restrict__ incl /*->rowptr*/,
               const int* __restrict__ boff) {
    const int i = blockIdx.x * 256 + threadIdx.x;
    if (i >= N_NODES) return;
    incl[i] = incl[i] - count[i] + boff[blockIdx.x];  // exclusive prefix
}

// ---------------------------------------------------------------------------
// K4: atomic-free scatter — pos = rowptr[dst] + rank.  ONE 16B scattered
//     write per edge. Also emits edge_index output (float).
// ---------------------------------------------------------------------------
__global__ __launch_bounds__(256)
void k4_scatter(const int* __restrict__ src, const int* __restrict__ dst,
                const float* __restrict__ ea, const int* __restrict__ rank,
                const int* __restrict__ rowptr, int4* __restrict__ recs,
                float* __restrict__ out_ei) {
    int e = blockIdx.x * blockDim.x + threadIdx.x;
    if (e >= N_EDGES) return;
    const int d = dst[e];
    const int s = src[e];
    const int pos = rowptr[d] + rank[e];
    recs[pos] = make_int4(e, s, __float_as_int(ea[e]), 0);
    out_ei[e] = (float)s;
    out_ei[N_EDGES + e] = (float)d;
}

// ---------------------------------------------------------------------------
// K5: fused per-node GATv2. One wave per node; 8 edges in flight
//     (8 groups x 8 lanes; lane u owns cols 8u..8u+7, all in head u>>1).
//     One-exp online softmax (exp2-folded); groups flash-merge via shfl_xor.
// ---------------------------------------------------------------------------
__global__ __launch_bounds__(256)
void k5_node(const int4* __restrict__ recs,
             const int* __restrict__ rowptr, const int* __restrict__ count,
             const float* __restrict__ xl, const float* __restrict__ xr,
             const float* __restrict__ xres,
             const float* __restrict__ We, const float* __restrict__ att,
             const float* __restrict__ bias_out,
             float* __restrict__ out, float* __restrict__ out_alpha) {
    __shared__ float sc_lds[4][CAP][HEADS];   // 8 KB (scores pre-scaled by log2e)

    const int wv   = threadIdx.x >> 6;
    const int lane = threadIdx.x & 63;
    const int u    = lane & 7;            // col-octet: cols 8u..8u+7 (head u>>1)
    const int g    = lane >> 3;           // edge group 0..7
    const int n    = blockIdx.x * 4 + wv; // grid exact: 12500*4 = 50000

    const int base = rowptr[n];
    const int deg  = count[n];

    const float4 xrA = *(const float4*)(xr + (size_t)n * HD + 8 * u);
    const float4 xrB = *(const float4*)(xr + (size_t)n * HD + 8 * u + 4);
    const float4 WeA = *(const float4*)(We + 8 * u);
    const float4 WeB = *(const float4*)(We + 8 * u + 4);
    float4 atA = *(const float4*)(att + 8 * u);
    float4 atB = *(const float4*)(att + 8 * u + 4);
    atA.x *= LOG2E; atA.y *= LOG2E; atA.z *= LOG2E; atA.w *= LOG2E;
    atB.x *= LOG2E; atB.y *= LOG2E; atB.z *= LOG2E; atB.w *= LOG2E;

    float m = -INFINITY, dsum = 0.f;
    float4 accA = make_float4(0.f, 0.f, 0.f, 0.f);
    float4 accB = make_float4(0.f, 0.f, 0.f, 0.f);

    for (int c0 = 0; c0 < deg; c0 += 64) {
        const int nrem = min(64, deg - c0);
        int s_my = 0; float a_my = 0.f;
        if (lane < nrem) {
            const int4 r = recs[base + c0 + lane];   // coalesced 16B
            s_my = r.y;
            a_my = __int_as_float(r.z);
        }
        const int nchunk = (nrem + 7) >> 3;

        // prefetch chunk 0 for this group
        int   j   = g;
        bool  v   = j < nrem;
        int   s   = __shfl(s_my, j);
        float aev = __shfl(a_my, j);
        float4 xlA = make_float4(0.f, 0.f, 0.f, 0.f);
        float4 xlB = make_float4(0.f, 0.f, 0.f, 0.f);
        if (v) {
            xlA = *(const float4*)(xl + (size_t)s * HD + 8 * u);
            xlB = *(const float4*)(xl + (size_t)s * HD + 8 * u + 4);
        }

        for (int c = 0; c < nchunk; ++c) {
            const float4 curA = xlA, curB = xlB;
            const bool   curv = v;
            const float  ca   = aev;
            const int    cj   = 8 * c + g;
            // prefetch next chunk
            j = 8 * (c + 1) + g;
            v = j < nrem;
            s   = __shfl(s_my, j & 63);
            aev = __shfl(a_my, j & 63);
            if (v) {
                xlA = *(const float4*)(xl + (size_t)s * HD + 8 * u);
                xlB = *(const float4*)(xl + (size_t)s * HD + 8 * u + 4);
            }

            if (curv) {
                float f0 = curA.x + xrA.x + ca * WeA.x;
                float f1 = curA.y + xrA.y + ca * WeA.y;
                float f2 = curA.z + xrA.z + ca * WeA.z;
                float f3 = curA.w + xrA.w + ca * WeA.w;
                float f4 = curB.x + xrB.x + ca * WeB.x;
                float f5 = curB.y + xrB.y + ca * WeB.y;
                float f6 = curB.z + xrB.z + ca * WeB.z;
                float f7 = curB.w + xrB.w + ca * WeB.w;
                f0 = f0 > 0.f ? f0 : NEG_SLOPE * f0;
                f1 = f1 > 0.f ? f1 : NEG_SLOPE * f1;
                f2 = f2 > 0.f ? f2 : NEG_SLOPE * f2;
                f3 = f3 > 0.f ? f3 : NEG_SLOPE * f3;
                f4 = f4 > 0.f ? f4 : NEG_SLOPE * f4;
                f5 = f5 > 0.f ? f5 : NEG_SLOPE * f5;
                f6 = f6 > 0.f ? f6 : NEG_SLOPE * f6;
                f7 = f7 > 0.f ? f7 : NEG_SLOPE * f7;
                float p = f0 * atA.x + f1 * atA.y + f2 * atA.z + f3 * atA.w
                        + f4 * atB.x + f5 * atB.y + f6 * atB.z + f7 * atB.w;
                p += __shfl_xor(p, 1);     // head score (lanes 2h,2h+1 share)
                const int jj = c0 + cj;
                if (jj < CAP && (u & 1) == 0) sc_lds[wv][jj][u >> 1] = p;
                // one-exp online update: t = 2^(-|p-m|)
                const float t    = hw_exp2(-fabsf(p - m));   // m=-inf -> 0
                const bool  up   = (p >= m);
                const float scl  = up ? t : 1.f;
                const float pe   = up ? 1.f : t;
                m = fmaxf(m, p);
                dsum  = dsum * scl + pe;
                accA.x = accA.x * scl + pe * curA.x;
                accA.y = accA.y * scl + pe * curA.y;
                accA.z = accA.z * scl + pe * curA.z;
                accA.w = accA.w * scl + pe * curA.w;
                accB.x = accB.x * scl + pe * curB.x;
                accB.y = accB.y * scl + pe * curB.y;
                accB.z = accB.z * scl + pe * curB.z;
                accB.w = accB.w * scl + pe * curB.w;
            }
        }
    }

    // flash-merge the 8 groups (lanes u, u+8, ..., u+56 share a col slice)
#pragma unroll
    for (int off = 8; off <= 32; off <<= 1) {
        const float mo = __shfl_xor(m, off);
        const float d2 = __shfl_xor(dsum, off);
        float4 aA, aB;
        aA.x = __shfl_xor(accA.x, off); aA.y = __shfl_xor(accA.y, off);
        aA.z = __shfl_xor(accA.z, off); aA.w = __shfl_xor(accA.w, off);
        aB.x = __shfl_xor(accB.x, off); aB.y = __shfl_xor(accB.y, off);
        aB.z = __shfl_xor(accB.z, off); aB.w = __shfl_xor(accB.w, off);
        const float mm = fmaxf(m, mo);
        const float s1 = (m  == -INFINITY) ? 0.f : hw_exp2(m - mm);
        const float s2 = (mo == -INFINITY) ? 0.f : hw_exp2(mo - mm);
        dsum  = dsum * s1 + d2 * s2;
        accA.x = accA.x * s1 + aA.x * s2; accA.y = accA.y * s1 + aA.y * s2;
        accA.z = accA.z * s1 + aA.z * s2; accA.w = accA.w * s1 + aA.w * s2;
        accB.x = accB.x * s1 + aB.x * s2; accB.y = accB.y * s1 + aB.y * s2;
        accB.z = accB.z * s1 + aB.z * s2; accB.w = accB.w * s1 + aB.w * s2;
        m = mm;
    }
    const float inv = 1.f / (dsum + 1e-16f);

    // broadcast per-head m / inv (head h lives at lane 2h)
    const float m0 = __shfl(m, 0),  m1 = __shfl(m, 2);
    const float m2 = __shfl(m, 4),  m3 = __shfl(m, 6);
    const float i0 = __shfl(inv, 0), i1 = __shfl(inv, 2);
    const float i2 = __shfl(inv, 4), i3 = __shfl(inv, 6);

    __syncthreads();   // sc_lds visibility (uniform; each wave touches own slice)

    // alpha write pass (original edge order via record.eid)
    for (int jj = lane; jj < deg; jj += 64) {
        const int4 r = recs[base + jj];
        const int  e = r.x;
        float s0, s1, s2, s3;
        if (jj < CAP) {
            const float4 sc4 = *(const float4*)&sc_lds[wv][jj][0];
            s0 = sc4.x; s1 = sc4.y; s2 = sc4.z; s3 = sc4.w;
        } else {
            // slow path (deg > CAP): recompute from globals (log2-scaled)
            const int   sN  = r.y;
            const float aev = __int_as_float(r.z);
            float sc[4];
            for (int h2 = 0; h2 < 4; ++h2) {
                float a2 = 0.f;
                for (int d2 = 0; d2 < 16; ++d2) {
                    const int hd2 = h2 * 16 + d2;
                    float f = xl[(size_t)sN * HD + hd2] + xr[(size_t)n * HD + hd2]
                              + aev * We[hd2];
                    f = f > 0.f ? f : NEG_SLOPE * f;
                    a2 += f * att[hd2];
                }
                sc[h2] = a2 * LOG2E;
            }
            s0 = sc[0]; s1 = sc[1]; s2 = sc[2]; s3 = sc[3];
        }
        float4 a4;
        a4.x = hw_exp2(s0 - m0) * i0;
        a4.y = hw_exp2(s1 - m1) * i1;
        a4.z = hw_exp2(s2 - m2) * i2;
        a4.w = hw_exp2(s3 - m3) * i3;
        *(float4*)(out_alpha + (size_t)e * HEADS) = a4;
    }

    // final output (merged acc identical in all groups; group 0 writes)
    if (g == 0) {
        const float4 xsA = *(const float4*)(xres + (size_t)n * HD + 8 * u);
        const float4 xsB = *(const float4*)(xres + (size_t)n * HD + 8 * u + 4);
        const float4 bA  = *(const float4*)(bias_out + 8 * u);
        const float4 bB  = *(const float4*)(bias_out + 8 * u + 4);
        float4 o;
        o.x = accA.x * inv + bA.x + xsA.x;
        o.y = accA.y * inv + bA.y + xsA.y;
        o.z = accA.z * inv + bA.z + xsA.z;
        o.w = accA.w * inv + bA.w + xsA.w;
        o.x = o.x > 0.f ? o.x : __expf(o.x) - 1.f;
        o.y = o.y > 0.f ? o.y : __expf(o.y) - 1.f;
        o.z = o.z > 0.f ? o.z : __expf(o.z) - 1.f;
        o.w = o.w > 0.f ? o.w : __expf(o.w) - 1.f;
        *(float4*)(out + (size_t)n * HD + 8 * u) = o;
        o.x = accB.x * inv + bB.x + xsB.x;
        o.y = accB.y * inv + bB.y + xsB.y;
        o.z = accB.z * inv + bB.z + xsB.z;
        o.w = accB.w * inv + bB.w + xsB.w;
        o.x = o.x > 0.f ? o.x : __expf(o.x) - 1.f;
        o.y = o.y > 0.f ? o.y : __expf(o.y) - 1.f;
        o.z = o.z > 0.f ? o.z : __expf(o.z) - 1.f;
        o.w = o.w > 0.f ? o.w : __expf(o.w) - 1.f;
        *(float4*)(out + (size_t)n * HD + 8 * u + 4) = o;
    }
}

// ---------------------------------------------------------------------------
extern "C" void kernel_launch(void* const* d_in, const int* in_sizes, int n_in,
                              void* d_out, int out_size, void* d_ws, size_t ws_size,
                              hipStream_t stream) {
    const float* x        = (const float*)d_in[0];
    const int*   ei       = (const int*)d_in[1];
    const float* ea       = (const float*)d_in[2];
    const float* Wl       = (const float*)d_in[3];
    const float* bl       = (const float*)d_in[4];
    const float* Wr       = (const float*)d_in[5];
    const float* br       = (const float*)d_in[6];
    const float* We       = (const float*)d_in[7];
    const float* att      = (const float*)d_in[8];
    const float* bias_out = (const float*)d_in[9];
    const float* Wres     = (const float*)d_in[10];
    const float* bres     = (const float*)d_in[11];

    const int* src = ei;
    const int* dst = ei + N_EDGES;

    // output layout (tuple concat, float32): out | edge_index | alpha
    float* out       = (float*)d_out;
    float* out_ei    = out + (size_t)N_NODES * HD;
    float* out_alpha = out_ei + 2 * (size_t)N_EDGES;

    // workspace layout
    float* ws   = (float*)d_ws;
    float* xl   = ws;                               // N*HD
    float* xr   = xl + (size_t)N_NODES * HD;        // N*HD
    float* xres = xr + (size_t)N_NODES * HD;        // N*HD
    int* ibuf   = (int*)(xres + (size_t)N_NODES * HD);
    int* count  = ibuf;                             // N
    int* rowptr = count + N_NODES;                  // N
    int* bsum   = rowptr + N_NODES;                 // SCAN_BLOCKS
    int* boff   = bsum + SCAN_BLOCKS;               // SCAN_BLOCKS
    int* rank   = boff + SCAN_BLOCKS;               // E
    // 16B-align the record array
    size_t recoff = (size_t)(rank + N_EDGES - (int*)d_ws);
    recoff = (recoff + 3) & ~(size_t)3;
    int4* recs  = (int4*)((int*)d_ws + recoff);     // E records (16B each)

    k1_proj<<<(N_NODES + 31) / 32, 256, 0, stream>>>(x, Wl, bl, Wr, br, Wres, bres,
                                                     count, xl, xr, xres);
    k2_hist<<<N_EDGES / 256, 256, 0, stream>>>(dst, count, rank);
    k3a_scan1<<<SCAN_BLOCKS, 256, 0, stream>>>(count, rowptr, bsum);
    k3b_scan2<<<1, 256, 0, stream>>>(bsum, boff);
    k3c_scan3<<<SCAN_BLOCKS, 256, 0, stream>>>(count, rowptr, boff);
    k4_scatter<<<(N_EDGES + 255) / 256, 256, 0, stream>>>(src, dst, ea, rank,
                                                          rowptr, recs, out_ei);
    k5_node<<<N_NODES / 4, 256, 0, stream>>>(recs, rowptr, count,
                                             xl, xr, xres, We, att, bias_out,
                                             out, out_alpha);
}

// Round 10
// 262.839 us; speedup vs baseline: 1.2499x; 1.0221x over previous
//
#include <hip/hip_runtime.h>
#include <hip/hip_fp16.h>
#include <math.h>

// ---- problem constants (match reference) ----
#define N_NODES 50000
#define N_EDGES 800000
#define IN_DIM  128
#define HEADS   4
#define OUT_DIM 16
#define HD      64          // HEADS*OUT_DIM
#define NEG_SLOPE 0.2f
#define CAP     128         // per-node LDS score cache (deg > CAP -> slow path)
#define LOG2E   1.44269504088896340736f
#define DEFER_THR 8.0f      // defer-max rescale threshold (log2 units)

// hardware 2^x (v_exp_f32); avoids glibc __exp2f name collision
__device__ __forceinline__ float hw_exp2(float x) {
    return __builtin_amdgcn_exp2f(x);
}

// ---------------------------------------------------------------------------
// K1: node projections as a register-tiled GEMM fragment.
// 32 nodes/block (4 waves x 8 nodes). Lane = (g,u): u=col-quad, g=k-phase.
// xl is written in FP16 (halves k5's gather traffic); xr/xres stay fp32.
// Also zeroes count[].
// ---------------------------------------------------------------------------
__global__ __launch_bounds__(256)
void k1_proj(const float* __restrict__ x,
             const float* __restrict__ Wl, const float* __restrict__ bl,
             const float* __restrict__ Wr, const float* __restrict__ br,
             const float* __restrict__ Wres, const float* __restrict__ bres,
             int* __restrict__ count,
             __half* __restrict__ xlh, float* __restrict__ xr,
             float* __restrict__ xres) {
    __shared__ float xsT[IN_DIM][36];   // transposed x tile, pad->conflict-free reads
    const int base = blockIdx.x * 32;

    // free count-zeroing (replaces k0): 1563*256 = 400128 >= N_NODES
    const int gid = blockIdx.x * 256 + threadIdx.x;
    if (gid < N_NODES) count[gid] = 0;

    // stage x transposed: thread reads 4 consecutive float4 (64B) of one row
    {
        const float4* x4 = (const float4*)x;
#pragma unroll
        for (int r = 0; r < 4; ++r) {
            const int E    = threadIdx.x * 4 + r;   // float4 index in tile
            const int node = E >> 5;                // 32 float4 per node row
            const int kq   = E & 31;
            float4 v = make_float4(0.f, 0.f, 0.f, 0.f);
            if (base + node < N_NODES) v = x4[(size_t)(base + node) * 32 + kq];
            xsT[4 * kq + 0][node] = v.x;
            xsT[4 * kq + 1][node] = v.y;
            xsT[4 * kq + 2][node] = v.z;
            xsT[4 * kq + 3][node] = v.w;
        }
    }
    __syncthreads();

    const int lane = threadIdx.x & 63;
    const int wv   = threadIdx.x >> 6;
    const int u    = lane & 15;          // col-quad: cols 4u..4u+3
    const int g    = lane >> 4;          // k-phase 0..3
    const int n0   = wv * 8;             // first of this wave's 8 nodes

    float4 aL[8], aR[8], aS[8];
#pragma unroll
    for (int i = 0; i < 8; ++i) {
        aL[i] = make_float4(0.f, 0.f, 0.f, 0.f);
        aR[i] = make_float4(0.f, 0.f, 0.f, 0.f);
        aS[i] = make_float4(0.f, 0.f, 0.f, 0.f);
    }

    const float* pL = Wl   + g * HD + 4 * u;
    const float* pR = Wr   + g * HD + 4 * u;
    const float* pS = Wres + g * HD + 4 * u;

#pragma unroll 2
    for (int k0 = 0; k0 < IN_DIM; k0 += 4) {
        const int k = k0 + g;
        const float4 wl4 = *(const float4*)(pL + k0 * HD);
        const float4 wr4 = *(const float4*)(pR + k0 * HD);
        const float4 ws4 = *(const float4*)(pS + k0 * HD);
        const float4 xa  = *(const float4*)&xsT[k][n0];       // nodes n0..n0+3
        const float4 xb  = *(const float4*)&xsT[k][n0 + 4];   // nodes n0+4..n0+7
        const float xn[8] = {xa.x, xa.y, xa.z, xa.w, xb.x, xb.y, xb.z, xb.w};
#pragma unroll
        for (int i = 0; i < 8; ++i) {
            aL[i].x += xn[i] * wl4.x; aL[i].y += xn[i] * wl4.y;
            aL[i].z += xn[i] * wl4.z; aL[i].w += xn[i] * wl4.w;
            aR[i].x += xn[i] * wr4.x; aR[i].y += xn[i] * wr4.y;
            aR[i].z += xn[i] * wr4.z; aR[i].w += xn[i] * wr4.w;
            aS[i].x += xn[i] * ws4.x; aS[i].y += xn[i] * ws4.y;
            aS[i].z += xn[i] * ws4.z; aS[i].w += xn[i] * ws4.w;
        }
    }

    // merge partial sums across the 4 k-phases (lane bits 4-5)
#pragma unroll
    for (int off = 16; off <= 32; off <<= 1) {
#pragma unroll
        for (int i = 0; i < 8; ++i) {
            aL[i].x += __shfl_xor(aL[i].x, off); aL[i].y += __shfl_xor(aL[i].y, off);
            aL[i].z += __shfl_xor(aL[i].z, off); aL[i].w += __shfl_xor(aL[i].w, off);
            aR[i].x += __shfl_xor(aR[i].x, off); aR[i].y += __shfl_xor(aR[i].y, off);
            aR[i].z += __shfl_xor(aR[i].z, off); aR[i].w += __shfl_xor(aR[i].w, off);
            aS[i].x += __shfl_xor(aS[i].x, off); aS[i].y += __shfl_xor(aS[i].y, off);
            aS[i].z += __shfl_xor(aS[i].z, off); aS[i].w += __shfl_xor(aS[i].w, off);
        }
    }

    if (g == 0) {
        const float4 bl4 = *(const float4*)(bl   + 4 * u);
        const float4 br4 = *(const float4*)(br   + 4 * u);
        const float4 bs4 = *(const float4*)(bres + 4 * u);
#pragma unroll
        for (int i = 0; i < 8; ++i) {
            const int node = base + n0 + i;
            if (node < N_NODES) {
                const size_t off0 = (size_t)node * HD + 4 * u;
                // xl in fp16 (packed 4 halves = 8B)
                const __half2 h0 = __float22half2_rn(
                    make_float2(aL[i].x + bl4.x, aL[i].y + bl4.y));
                const __half2 h1 = __float22half2_rn(
                    make_float2(aL[i].z + bl4.z, aL[i].w + bl4.w));
                uint2 pk;
                pk.x = *(const unsigned int*)&h0;
                pk.y = *(const unsigned int*)&h1;
                *(uint2*)(xlh + off0) = pk;
                float4 o;
                o.x = aR[i].x + br4.x; o.y = aR[i].y + br4.y;
                o.z = aR[i].z + br4.z; o.w = aR[i].w + br4.w;
                *(float4*)(xr + off0) = o;
                o.x = aS[i].x + bs4.x; o.y = aS[i].y + bs4.y;
                o.z = aS[i].z + bs4.z; o.w = aS[i].w + bs4.w;
                *(float4*)(xres + off0) = o;
            }
        }
    }
}

// ---------------------------------------------------------------------------
// K2: histogram of dst + per-edge rank (the atomic's return value).
// ---------------------------------------------------------------------------
__global__ __launch_bounds__(256)
void k2_hist(const int* __restrict__ dst, int* __restrict__ count,
             int* __restrict__ rank) {
    int e = blockIdx.x * blockDim.x + threadIdx.x;
    if (e < N_EDGES) rank[e] = atomicAdd(&count[dst[e]], 1);
}

// ---------------------------------------------------------------------------
// K3a/b/c: two-level exclusive scan of count -> rowptr
// ---------------------------------------------------------------------------
#define SCAN_BLOCKS 196   // ceil(50000/256)

__global__ __launch_bounds__(256)
void k3a_scan1(const int* __restrict__ count, int* __restrict__ incl,
               int* __restrict__ bsum) {
    __shared__ int s[256];
    const int t = threadIdx.x;
    const int i = blockIdx.x * 256 + t;
    int c = (i < N_NODES) ? count[i] : 0;
    s[t] = c;
    __syncthreads();
    for (int off = 1; off < 256; off <<= 1) {
        int v = (t >= off) ? s[t - off] : 0;
        __syncthreads();
        s[t] += v;
        __syncthreads();
    }
    if (i < N_NODES) incl[i] = s[t];
    if (t == 255) bsum[blockIdx.x] = s[255];
}

__global__ __launch_bounds__(256)
void k3b_scan2(int* __restrict__ bsum, int* __restrict__ boff) {
    __shared__ int s[256];
    const int t = threadIdx.x;
    int c = (t < SCAN_BLOCKS) ? bsum[t] : 0;
    s[t] = c;
    __syncthreads();
    for (int off = 1; off < 256; off <<= 1) {
        int v = (t >= off) ? s[t - off] : 0;
        __syncthreads();
        s[t] += v;
        __syncthreads();
    }
    if (t < SCAN_BLOCKS) boff[t] = s[t] - c;   // exclusive
}

__global__ __launch_bounds__(256)
void k3c_scan3(const int* __restrict__ count, int* __restrict__ incl /*->rowptr*/,
               const int* __restrict__ boff) {
    const int i = blockIdx.x * 256 + threadIdx.x;
    if (i >= N_NODES) return;
    incl[i] = incl[i] - count[i] + boff[blockIdx.x];  // exclusive prefix
}

// ---------------------------------------------------------------------------
// K4: atomic-free scatter — pos = rowptr[dst] + rank.  ONE 16B scattered
//     write per edge. Also emits edge_index output (float).
// ---------------------------------------------------------------------------
__global__ __launch_bounds__(256)
void k4_scatter(const int* __restrict__ src, const int* __restrict__ dst,
                const float* __restrict__ ea, const int* __restrict__ rank,
                const int* __restrict__ rowptr, int4* __restrict__ recs,
                float* __restrict__ out_ei) {
    int e = blockIdx.x * blockDim.x + threadIdx.x;
    if (e >= N_EDGES) return;
    const int d = dst[e];
    const int s = src[e];
    const int pos = rowptr[d] + rank[e];
    recs[pos] = make_int4(e, s, __float_as_int(ea[e]), 0);
    out_ei[e] = (float)s;
    out_ei[N_EDGES + e] = (float)d;
}

// ---------------------------------------------------------------------------
// K5: fused per-node GATv2. One wave per node; 8 edge groups x 8 lanes,
//     lane u owns cols 8u..8u+7 (head u>>1). FP16 xl gather (one 16B
//     load/lane/edge), depth-2 software pipeline (bufA/bufB), defer-max
//     online softmax (rescale only when max grows > 8 log2-units).
// ---------------------------------------------------------------------------
__global__ __launch_bounds__(256)
void k5_node(const int4* __restrict__ recs,
             const int* __restrict__ rowptr, const int* __restrict__ count,
             const __half* __restrict__ xlh, const float* __restrict__ xr,
             const float* __restrict__ xres,
             const float* __restrict__ We, const float* __restrict__ att,
             const float* __restrict__ bias_out,
             float* __restrict__ out, float* __restrict__ out_alpha) {
    __shared__ float sc_lds[4][CAP][HEADS];   // 8 KB (scores pre-scaled by log2e)

    const int wv   = threadIdx.x >> 6;
    const int lane = threadIdx.x & 63;
    const int u    = lane & 7;            // col-octet: cols 8u..8u+7 (head u>>1)
    const int g    = lane >> 3;           // edge group 0..7
    const int n    = blockIdx.x * 4 + wv; // grid exact: 12500*4 = 50000

    const int base = rowptr[n];
    const int deg  = count[n];

    const float4 xrA = *(const float4*)(xr + (size_t)n * HD + 8 * u);
    const float4 xrB = *(const float4*)(xr + (size_t)n * HD + 8 * u + 4);
    const float4 WeA = *(const float4*)(We + 8 * u);
    const float4 WeB = *(const float4*)(We + 8 * u + 4);
    float4 atA = *(const float4*)(att + 8 * u);
    float4 atB = *(const float4*)(att + 8 * u + 4);
    atA.x *= LOG2E; atA.y *= LOG2E; atA.z *= LOG2E; atA.w *= LOG2E;
    atB.x *= LOG2E; atB.y *= LOG2E; atB.z *= LOG2E; atB.w *= LOG2E;

    float m = -128.f, dsum = 0.f;    // defer-max state (log2 units)
    float4 accA = make_float4(0.f, 0.f, 0.f, 0.f);
    float4 accB = make_float4(0.f, 0.f, 0.f, 0.f);

    // per-edge update: convert fp16 row slice, score, defer-max accumulate
    auto PROCESS = [&](const float4& raw, float ca, int jj) {
        const __half2* hp = (const __half2*)&raw;
        const float2 p0 = __half22float2(hp[0]);
        const float2 p1 = __half22float2(hp[1]);
        const float2 p2 = __half22float2(hp[2]);
        const float2 p3 = __half22float2(hp[3]);
        float f0 = p0.x + xrA.x + ca * WeA.x;
        float f1 = p0.y + xrA.y + ca * WeA.y;
        float f2 = p1.x + xrA.z + ca * WeA.z;
        float f3 = p1.y + xrA.w + ca * WeA.w;
        float f4 = p2.x + xrB.x + ca * WeB.x;
        float f5 = p2.y + xrB.y + ca * WeB.y;
        float f6 = p3.x + xrB.z + ca * WeB.z;
        float f7 = p3.y + xrB.w + ca * WeB.w;
        f0 = fmaxf(f0, NEG_SLOPE * f0);   // leaky-relu (slope<1)
        f1 = fmaxf(f1, NEG_SLOPE * f1);
        f2 = fmaxf(f2, NEG_SLOPE * f2);
        f3 = fmaxf(f3, NEG_SLOPE * f3);
        f4 = fmaxf(f4, NEG_SLOPE * f4);
        f5 = fmaxf(f5, NEG_SLOPE * f5);
        f6 = fmaxf(f6, NEG_SLOPE * f6);
        f7 = fmaxf(f7, NEG_SLOPE * f7);
        float p = f0 * atA.x + f1 * atA.y + f2 * atA.z + f3 * atA.w
                + f4 * atB.x + f5 * atB.y + f6 * atB.z + f7 * atB.w;
        p += __shfl_xor(p, 1);            // head score (lanes 2h,2h+1 share)
        if (jj < CAP && (u & 1) == 0) sc_lds[wv][jj][u >> 1] = p;
        const float diff = p - m;
        if (diff > DEFER_THR) {           // rare rescale
            const float scl = hw_exp2(-diff);
            dsum *= scl;
            accA.x *= scl; accA.y *= scl; accA.z *= scl; accA.w *= scl;
            accB.x *= scl; accB.y *= scl; accB.z *= scl; accB.w *= scl;
            m = p;
        }
        const float pe = hw_exp2(p - m);  // bounded by 2^DEFER_THR
        dsum += pe;
        accA.x += pe * p0.x; accA.y += pe * p0.y;
        accA.z += pe * p1.x; accA.w += pe * p1.y;
        accB.x += pe * p2.x; accB.y += pe * p2.y;
        accB.z += pe * p3.x; accB.w += pe * p3.y;
    };

    for (int c0 = 0; c0 < deg; c0 += 64) {
        const int nrem = min(64, deg - c0);
        int s_my = 0; float a_my = 0.f;
        if (lane < nrem) {
            const int4 r = recs[base + c0 + lane];   // coalesced 16B
            s_my = r.y;
            a_my = __int_as_float(r.z);
        }
        const int nchunk = (nrem + 7) >> 3;

        // prologue: prefetch chunks 0 (A) and 1 (B)
        int   jA = g;
        bool  vA = jA < nrem;
        int   sA = __shfl(s_my, jA & 63);
        float aA = __shfl(a_my, jA & 63);
        float4 bufA = make_float4(0.f, 0.f, 0.f, 0.f);
        if (vA) bufA = *(const float4*)(xlh + (size_t)sA * HD + 8 * u);
        int   jB = 8 + g;
        bool  vB = jB < nrem;
        int   sB = __shfl(s_my, jB & 63);
        float aB = __shfl(a_my, jB & 63);
        float4 bufB = make_float4(0.f, 0.f, 0.f, 0.f);
        if (vB) bufB = *(const float4*)(xlh + (size_t)sB * HD + 8 * u);

        for (int c = 0; c < nchunk; c += 2) {
            // stage A: compute chunk c, prefetch chunk c+2
            {
                const float4 cur  = bufA;
                const bool   curv = vA;
                const float  ca   = aA;
                const int    jj   = c0 + 8 * c + g;
                jA = 8 * (c + 2) + g;
                vA = jA < nrem;
                sA = __shfl(s_my, jA & 63);
                aA = __shfl(a_my, jA & 63);
                if (vA) bufA = *(const float4*)(xlh + (size_t)sA * HD + 8 * u);
                if (curv) PROCESS(cur, ca, jj);
            }
            // stage B: compute chunk c+1, prefetch chunk c+3
            {
                const float4 cur  = bufB;
                const bool   curv = vB;
                const float  ca   = aB;
                const int    jj   = c0 + 8 * (c + 1) + g;
                jB = 8 * (c + 3) + g;
                vB = jB < nrem;
                sB = __shfl(s_my, jB & 63);
                aB = __shfl(a_my, jB & 63);
                if (vB) bufB = *(const float4*)(xlh + (size_t)sB * HD + 8 * u);
                if (curv) PROCESS(cur, ca, jj);
            }
        }
    }

    // flash-merge the 8 groups (m=-128 floor: plain exp2 math, no inf guards)
#pragma unroll
    for (int off = 8; off <= 32; off <<= 1) {
        const float mo = __shfl_xor(m, off);
        const float d2 = __shfl_xor(dsum, off);
        float4 aA2, aB2;
        aA2.x = __shfl_xor(accA.x, off); aA2.y = __shfl_xor(accA.y, off);
        aA2.z = __shfl_xor(accA.z, off); aA2.w = __shfl_xor(accA.w, off);
        aB2.x = __shfl_xor(accB.x, off); aB2.y = __shfl_xor(accB.y, off);
        aB2.z = __shfl_xor(accB.z, off); aB2.w = __shfl_xor(accB.w, off);
        const float mm = fmaxf(m, mo);
        const float s1 = hw_exp2(m - mm);
        const float s2 = hw_exp2(mo - mm);
        dsum  = dsum * s1 + d2 * s2;
        accA.x = accA.x * s1 + aA2.x * s2; accA.y = accA.y * s1 + aA2.y * s2;
        accA.z = accA.z * s1 + aA2.z * s2; accA.w = accA.w * s1 + aA2.w * s2;
        accB.x = accB.x * s1 + aB2.x * s2; accB.y = accB.y * s1 + aB2.y * s2;
        accB.z = accB.z * s1 + aB2.z * s2; accB.w = accB.w * s1 + aB2.w * s2;
        m = mm;
    }
    const float inv = 1.f / (dsum + 1e-16f);

    // broadcast per-head m / inv (head h lives at lane 2h)
    const float m0 = __shfl(m, 0),  m1 = __shfl(m, 2);
    const float m2 = __shfl(m, 4),  m3 = __shfl(m, 6);
    const float i0 = __shfl(inv, 0), i1 = __shfl(inv, 2);
    const float i2 = __shfl(inv, 4), i3 = __shfl(inv, 6);

    __syncthreads();   // sc_lds visibility (uniform; each wave touches own slice)

    // alpha write pass (original edge order via record.eid)
    for (int jj = lane; jj < deg; jj += 64) {
        const int4 r = recs[base + jj];
        const int  e = r.x;
        float s0, s1, s2, s3;
        if (jj < CAP) {
            const float4 sc4 = *(const float4*)&sc_lds[wv][jj][0];
            s0 = sc4.x; s1 = sc4.y; s2 = sc4.z; s3 = sc4.w;
        } else {
            // slow path (deg > CAP): recompute from globals (log2-scaled)
            const int   sN  = r.y;
            const float aev = __int_as_float(r.z);
            float sc[4];
            for (int h2 = 0; h2 < 4; ++h2) {
                float a2 = 0.f;
                for (int d2 = 0; d2 < 16; ++d2) {
                    const int hd2 = h2 * 16 + d2;
                    float f = __half2float(xlh[(size_t)sN * HD + hd2])
                              + xr[(size_t)n * HD + hd2] + aev * We[hd2];
                    f = fmaxf(f, NEG_SLOPE * f);
                    a2 += f * att[hd2];
                }
                sc[h2] = a2 * LOG2E;
            }
            s0 = sc[0]; s1 = sc[1]; s2 = sc[2]; s3 = sc[3];
        }
        float4 a4;
        a4.x = hw_exp2(s0 - m0) * i0;
        a4.y = hw_exp2(s1 - m1) * i1;
        a4.z = hw_exp2(s2 - m2) * i2;
        a4.w = hw_exp2(s3 - m3) * i3;
        *(float4*)(out_alpha + (size_t)e * HEADS) = a4;
    }

    // final output (merged acc identical in all groups; group 0 writes)
    if (g == 0) {
        const float4 xsA = *(const float4*)(xres + (size_t)n * HD + 8 * u);
        const float4 xsB = *(const float4*)(xres + (size_t)n * HD + 8 * u + 4);
        const float4 bA  = *(const float4*)(bias_out + 8 * u);
        const float4 bB  = *(const float4*)(bias_out + 8 * u + 4);
        float4 o;
        o.x = accA.x * inv + bA.x + xsA.x;
        o.y = accA.y * inv + bA.y + xsA.y;
        o.z = accA.z * inv + bA.z + xsA.z;
        o.w = accA.w * inv + bA.w + xsA.w;
        o.x = o.x > 0.f ? o.x : __expf(o.x) - 1.f;
        o.y = o.y > 0.f ? o.y : __expf(o.y) - 1.f;
        o.z = o.z > 0.f ? o.z : __expf(o.z) - 1.f;
        o.w = o.w > 0.f ? o.w : __expf(o.w) - 1.f;
        *(float4*)(out + (size_t)n * HD + 8 * u) = o;
        o.x = accB.x * inv + bB.x + xsB.x;
        o.y = accB.y * inv + bB.y + xsB.y;
        o.z = accB.z * inv + bB.z + xsB.z;
        o.w = accB.w * inv + bB.w + xsB.w;
        o.x = o.x > 0.f ? o.x : __expf(o.x) - 1.f;
        o.y = o.y > 0.f ? o.y : __expf(o.y) - 1.f;
        o.z = o.z > 0.f ? o.z : __expf(o.z) - 1.f;
        o.w = o.w > 0.f ? o.w : __expf(o.w) - 1.f;
        *(float4*)(out + (size_t)n * HD + 8 * u + 4) = o;
    }
}

// ---------------------------------------------------------------------------
extern "C" void kernel_launch(void* const* d_in, const int* in_sizes, int n_in,
                              void* d_out, int out_size, void* d_ws, size_t ws_size,
                              hipStream_t stream) {
    const float* x        = (const float*)d_in[0];
    const int*   ei       = (const int*)d_in[1];
    const float* ea       = (const float*)d_in[2];
    const float* Wl       = (const float*)d_in[3];
    const float* bl       = (const float*)d_in[4];
    const float* Wr       = (const float*)d_in[5];
    const float* br       = (const float*)d_in[6];
    const float* We       = (const float*)d_in[7];
    const float* att      = (const float*)d_in[8];
    const float* bias_out = (const float*)d_in[9];
    const float* Wres     = (const float*)d_in[10];
    const float* bres     = (const float*)d_in[11];

    const int* src = ei;
    const int* dst = ei + N_EDGES;

    // output layout (tuple concat, float32): out | edge_index | alpha
    float* out       = (float*)d_out;
    float* out_ei    = out + (size_t)N_NODES * HD;
    float* out_alpha = out_ei + 2 * (size_t)N_EDGES;

    // workspace layout
    float* ws    = (float*)d_ws;
    __half* xlh  = (__half*)ws;                     // N*HD halves (= N*HD/2 floats)
    float* xr    = ws + (size_t)N_NODES * HD / 2;   // N*HD
    float* xres  = xr + (size_t)N_NODES * HD;       // N*HD
    int* ibuf    = (int*)(xres + (size_t)N_NODES * HD);
    int* count   = ibuf;                            // N
    int* rowptr  = count + N_NODES;                 // N
    int* bsum    = rowptr + N_NODES;                // SCAN_BLOCKS
    int* boff    = bsum + SCAN_BLOCKS;              // SCAN_BLOCKS
    int* rank    = boff + SCAN_BLOCKS;              // E
    // 16B-align the record array
    size_t recoff = (size_t)(rank + N_EDGES - (int*)d_ws);
    recoff = (recoff + 3) & ~(size_t)3;
    int4* recs  = (int4*)((int*)d_ws + recoff);     // E records (16B each)

    k1_proj<<<(N_NODES + 31) / 32, 256, 0, stream>>>(x, Wl, bl, Wr, br, Wres, bres,
                                                     count, xlh, xr, xres);
    k2_hist<<<N_EDGES / 256, 256, 0, stream>>>(dst, count, rank);
    k3a_scan1<<<SCAN_BLOCKS, 256, 0, stream>>>(count, rowptr, bsum);
    k3b_scan2<<<1, 256, 0, stream>>>(bsum, boff);
    k3c_scan3<<<SCAN_BLOCKS, 256, 0, stream>>>(count, rowptr, boff);
    k4_scatter<<<(N_EDGES + 255) / 256, 256, 0, stream>>>(src, dst, ea, rank,
                                                          rowptr, recs, out_ei);
    k5_node<<<N_NODES / 4, 256, 0, stream>>>(recs, rowptr, count,
                                             xlh, xr, xres, We, att, bias_out,
                                             out, out_alpha);
}